// Round 2
// baseline (967.398 us; speedup 1.0000x reference)
//
#include <hip/hip_runtime.h>

// dims
#define BB 2
#define SS 1024
#define HH 8
#define DD 64
#define RR 32
#define KK 128
#define ZLEN 1536            // 4K + S
#define ZROW 1152            // staged z positions [K, K+S+K) per (b,r,h,d)
#define HD 512               // H*D

// ---- async global->LDS DMA helpers (wave-wide; LDS dest = uniform base + lane*size) ----
__device__ __forceinline__ void dma16(const float* g, float* l) {
    const int lane = threadIdx.x & 63;
    __builtin_amdgcn_global_load_lds(
        (const __attribute__((address_space(1))) void*)(g + (lane << 2)),
        (__attribute__((address_space(3))) void*)l, 16, 0, 0);
}
__device__ __forceinline__ void dma4(const float* g, float* l) {
    const int lane = threadIdx.x & 63;
    __builtin_amdgcn_global_load_lds(
        (const __attribute__((address_space(1))) void*)(g + lane),
        (__attribute__((address_space(3))) void*)l, 4, 0, 0);
}

// block = (r, h, b); 256 threads; thread t computes s = 4t..4t+3 for all 64 d.
// Double-buffered z/w staging: prefetch d+1 while computing d; barrier drain ~free.
__global__ __launch_bounds__(256) void convspe_kernel(
    const float* __restrict__ q, const float* __restrict__ kmat,
    const float* __restrict__ wq, const float* __restrict__ wk,
    const float* __restrict__ z, float* __restrict__ out)
{
    __shared__ __align__(16) float zbuf[2][ZROW];     // 9.2 KB
    __shared__ __align__(16) float wbuf[2][2 * KK];   // 2 KB  (wq row at [0..128), wk at [128..256))

    const int tid = threadIdx.x;
    const int wave = tid >> 6;
    const int r = blockIdx.x, h = blockIdx.y, b = blockIdx.z;

    const size_t qkbase = (size_t)b * (SS * HD) + (size_t)h * DD;
    const size_t obase  = (size_t)b * (SS * HH * RR) + (size_t)h * RR + (size_t)r;

    // stage z row (1152 floats) + both 128-float weight rows for depth d into buffer p.
    // Work split across the 4 waves (each global_load_lds is per-wave).
    auto stage = [&](int d, int p) {
        const float* zg  = z  + (size_t)((b * RR + r) * HD + h * DD + d) * ZLEN + KK;
        const float* wqg = wq + (size_t)(h * DD + d) * KK;
        const float* wkg = wk + (size_t)(h * DD + d) * KK;
        switch (wave) {
        case 0:
            dma16(zg,        &zbuf[p][0]);
            dma16(zg + 256,  &zbuf[p][256]);
            break;
        case 1:
            dma16(zg + 512,  &zbuf[p][512]);
            dma16(zg + 768,  &zbuf[p][768]);
            break;
        case 2:
            dma4(zg + 1024,  &zbuf[p][1024]);
            dma4(zg + 1088,  &zbuf[p][1088]);
            dma4(wqg,        &wbuf[p][0]);
            dma4(wqg + 64,   &wbuf[p][64]);
            break;
        case 3:
            dma4(wkg,        &wbuf[p][128]);
            dma4(wkg + 64,   &wbuf[p][192]);
            break;
        }
    };

    float qacc[4] = {0.f, 0.f, 0.f, 0.f};
    float kacc[4] = {0.f, 0.f, 0.f, 0.f};

    stage(0, 0);
    __syncthreads();          // implies vmcnt(0) drain -> buf 0 ready

    #pragma unroll 2
    for (int d = 0; d < DD; ++d) {
        const int p = d & 1;

        // per-thread q/k scale values for this d (scattered, L1/L2-warm; used ~2048 cyc later)
        float qv[4], kv[4];
        const size_t qb = qkbase + (size_t)d;
        #pragma unroll
        for (int i = 0; i < 4; ++i) {
            qv[i] = q[qb + (size_t)(4 * tid + i) * HD];
            kv[i] = kmat[qb + (size_t)(4 * tid + i) * HD];
        }

        // async prefetch next depth into the other buffer
        if (d + 1 < DD) stage(d + 1, p ^ 1);

        // depthwise conv for this d: cq = conv(z, wk) (-> qbar), ck = conv(z, wq) (-> kbar)
        const float4* Z4  = (const float4*)zbuf[p];
        const float4* WQ4 = (const float4*)&wbuf[p][0];
        const float4* WK4 = (const float4*)&wbuf[p][KK];

        float cq[4] = {0.f, 0.f, 0.f, 0.f};
        float ck[4] = {0.f, 0.f, 0.f, 0.f};
        float4 za = Z4[tid];                    // z[4t .. 4t+3]
        #pragma unroll
        for (int k4 = 0; k4 < 32; ++k4) {
            const float4 zb = Z4[tid + k4 + 1];  // max idx 287 < 288, in range
            const float4 w_q = WQ4[k4];          // uniform -> LDS broadcast
            const float4 w_k = WK4[k4];
            float zw[8];
            zw[0] = za.x; zw[1] = za.y; zw[2] = za.z; zw[3] = za.w;
            zw[4] = zb.x; zw[5] = zb.y; zw[6] = zb.z; zw[7] = zb.w;
            #pragma unroll
            for (int kj = 0; kj < 4; ++kj) {
                const float wqv = (kj == 0) ? w_q.x : (kj == 1) ? w_q.y : (kj == 2) ? w_q.z : w_q.w;
                const float wkv = (kj == 0) ? w_k.x : (kj == 1) ? w_k.y : (kj == 2) ? w_k.z : w_k.w;
                #pragma unroll
                for (int i = 0; i < 4; ++i) {
                    cq[i] = fmaf(wkv, zw[kj + i], cq[i]);   // qbar uses wk (the swap)
                    ck[i] = fmaf(wqv, zw[kj + i], ck[i]);   // kbar uses wq
                }
            }
            za = zb;
        }

        // scale by q/k feature value and accumulate over d
        #pragma unroll
        for (int i = 0; i < 4; ++i) {
            qacc[i] = fmaf(qv[i], cq[i], qacc[i]);
            kacc[i] = fmaf(kv[i], ck[i], kacc[i]);
        }

        __syncthreads();      // drains vmcnt(0): prefetch for d+1 complete; reuse-safe swap
    }

    // store: qhat at [b,s,h,r], khat at +B*S*H*R
    #pragma unroll
    for (int i = 0; i < 4; ++i) {
        const int s = 4 * tid + i;
        out[obase + (size_t)s * (HH * RR)] = qacc[i];
        out[(size_t)(BB * SS * HH * RR) + obase + (size_t)s * (HH * RR)] = kacc[i];
    }
}

extern "C" void kernel_launch(void* const* d_in, const int* in_sizes, int n_in,
                              void* d_out, int out_size, void* d_ws, size_t ws_size,
                              hipStream_t stream) {
    const float* q  = (const float*)d_in[0];
    const float* k  = (const float*)d_in[1];
    const float* wq = (const float*)d_in[2];
    const float* wk = (const float*)d_in[3];
    const float* z  = (const float*)d_in[4];
    float* out = (float*)d_out;

    dim3 grid(RR, HH, BB);   // 512 blocks
    dim3 block(256);
    hipLaunchKernelGGL(convspe_kernel, grid, block, 0, stream, q, k, wq, wk, z, out);
}